// Round 1
// baseline (173.682 us; speedup 1.0000x reference)
//
#include <hip/hip_runtime.h>

// HitTheMiddleModel: per-row physics sim + 1e-10 * tiny linear.
// R6 = R5 with halo loads replaced by wave shuffles.
//   Thread q owns output float4 O4[q]. Inputs needed are floats 4q-2..4q+5,
//   i.e. window w2..w9 where w-index i <-> global float 4q-4+i:
//     one b128 load X4[q]   -> w4..w7  (floats 4q..4q+3)
//     w2,w3 = lane-1's C.z,C.w  -> __shfl_up by 1
//     w8,w9 = lane+1's C.x,C.y  -> __shfl_down by 1
//   Wave-edge lanes (0 and 63) fetch their 8B halo via ONE predicated global
//   load (2 active lanes/wave). Per-thread mem ops drop 3 loads -> ~1.03.
//   Phase m = q%3 handled by cndmask selects (no divergence). No LDS tiles,
//   no barriers; sim_row/sel3 arithmetic is bit-identical to R5.
// Clamp safety: q==0 -> phase 0, w2/w3 unused; last q (n4=3*2^21) -> phase 2,
//   w8/w9 unused. Clamped junk is never consumed.
// Partial-wave safety: q is clamped to n4-1 for loads/shuffles (all lanes stay
//   active so shuffles are well-defined); the store is predicated on q<n4, and
//   any lane whose right neighbor is clamped takes the edge-load path.

__device__ __forceinline__ void sim_row(float x0, float x1, float x2,
                                        const float* Wv, const float* bv,
                                        float& pos_o, float& vel_o, float& rew_o) {
    float vel = x1 + x2;
    float pos = x0 + vel;
    bool hit = (pos > 10.0f) || (pos < -10.0f);
    vel = hit ? -vel : vel;
    pos = fminf(10.0f, fmaxf(-10.0f, pos));
    float reward = -pos * pos;
    float y0 = fmaf(x0, Wv[0], fmaf(x1, Wv[1], fmaf(x2, Wv[2], bv[0])));
    float y1 = fmaf(x0, Wv[3], fmaf(x1, Wv[4], fmaf(x2, Wv[5], bv[1])));
    float y2 = fmaf(x0, Wv[6], fmaf(x1, Wv[7], fmaf(x2, Wv[8], bv[2])));
    pos_o = fmaf(1e-10f, y0, pos);
    vel_o = fmaf(1e-10f, y1, vel);
    rew_o = fmaf(1e-10f, y2, reward);
}

// 3-way select, branch-free (2 cndmask).
__device__ __forceinline__ float sel3(int m, float a, float b, float c) {
    float r = (m == 1) ? b : c;
    return (m == 0) ? a : r;
}

__global__ __launch_bounds__(256) void HitTheMiddleModel_kernel(
        const float4* __restrict__ X4,
        const float* __restrict__ X,
        const float* __restrict__ W,
        const float* __restrict__ B,
        float4* __restrict__ O4,
        long long n4, long long nfloats) {
    long long q = (long long)blockIdx.x * blockDim.x + threadIdx.x;
    long long qc = (q < n4) ? q : (n4 - 1);   // keep all lanes active for shuffles
    int lane = (int)(threadIdx.x & 63);

    float Wv[9];
#pragma unroll
    for (int i = 0; i < 9; ++i) Wv[i] = W[i];
    float bv[3] = {B[0], B[1], B[2]};

    // Single center load: 16B/lane, lane-contiguous.
    float4 C = X4[qc];

    // Halos from neighbor lanes' center loads.
    float w2 = __shfl_up(C.z, 1, 64);     // float 4q-2 (lane-1's C.z)
    float w3 = __shfl_up(C.w, 1, 64);     // float 4q-1
    float w8 = __shfl_down(C.x, 1, 64);   // float 4q+4 (lane+1's C.x)
    float w9 = __shfl_down(C.y, 1, 64);   // float 4q+5

    // Wave-edge lanes (and lanes whose right neighbor was clamped) fix up their
    // halo with one predicated 8B global load. 2 active lanes per full wave.
    bool leftEdge  = (lane == 0);
    bool rightEdge = (!leftEdge) && ((lane == 63) || (qc + 1 >= n4));
    if (leftEdge || rightEdge) {
        long long a;
        if (leftEdge) {
            a = 4 * qc - 2;                       // even -> 8B aligned
            if (a < 0) a = 0;                     // q==0: unused (phase 0)
        } else {
            a = 4 * qc + 4;
            if (a > nfloats - 2) a = nfloats - 2; // last q: unused (phase 2)
        }
        float2 e = *(const float2*)(X + a);
        if (leftEdge) { w2 = e.x; w3 = e.y; }
        else          { w8 = e.x; w9 = e.y; }
    }

    float w4 = C.x, w5 = C.y, w6 = C.z, w7 = C.w;

    int m = (int)((unsigned long long)qc % 3ull);

    // Row A covers output float 4q (component m); row B is the next row.
    float a0 = sel3(m, w4, w3, w2);
    float a1 = sel3(m, w5, w4, w3);
    float a2 = sel3(m, w6, w5, w4);
    float b0 = sel3(m, w7, w6, w5);
    float b1 = sel3(m, w8, w7, w6);
    float b2 = sel3(m, w9, w8, w7);

    float pA, vA, rA, pB, vB, rB;
    sim_row(a0, a1, a2, Wv, bv, pA, vA, rA);
    sim_row(b0, b1, b2, Wv, bv, pB, vB, rB);

    float4 r;
    r.x = sel3(m, pA, vA, rA);
    r.y = sel3(m, vA, rA, pB);
    r.z = sel3(m, rA, pB, vB);
    r.w = sel3(m, pB, vB, rB);
    if (q < n4) O4[q] = r;
}

// Scalar tail for nfloats % 4 != 0 (never launched for B = 2^23).
__global__ void HitTheMiddleModel_tail(
        const float* __restrict__ X, const float* __restrict__ W,
        const float* __restrict__ B, float* __restrict__ O,
        long long startFloat, long long nfloats) {
    long long g = startFloat + (long long)blockIdx.x * blockDim.x + threadIdx.x;
    if (g >= nfloats) return;
    float Wv[9];
    for (int i = 0; i < 9; ++i) Wv[i] = W[i];
    float bv[3] = {B[0], B[1], B[2]};
    long long row = g / 3;
    int c = (int)(g % 3);
    float x0 = X[3 * row], x1 = X[3 * row + 1], x2 = X[3 * row + 2];
    float p, v, rw;
    sim_row(x0, x1, x2, Wv, bv, p, v, rw);
    O[g] = (c == 0) ? p : (c == 1) ? v : rw;
}

extern "C" void kernel_launch(void* const* d_in, const int* in_sizes, int n_in,
                              void* d_out, int out_size, void* d_ws, size_t ws_size,
                              hipStream_t stream) {
    const float* x = (const float*)d_in[0];
    const float* W = (const float*)d_in[1];
    const float* b = (const float*)d_in[2];
    float* out = (float*)d_out;

    long long nfloats = (long long)in_sizes[0];   // 3 * rows
    long long n4 = nfloats / 4;                   // full float4s

    const int block = 256;
    long long grid = (n4 + block - 1) / block;
    HitTheMiddleModel_kernel<<<(int)grid, block, 0, stream>>>(
        (const float4*)x, x, W, b, (float4*)out, n4, nfloats);

    long long startFloat = 4 * n4;
    if (startFloat < nfloats) {
        long long tailN = nfloats - startFloat;
        int tgrid = (int)((tailN + 255) / 256);
        HitTheMiddleModel_tail<<<tgrid, 256, 0, stream>>>(
            x, W, b, out, startFloat, nfloats);
    }
}